// Round 2
// baseline (536.547 us; speedup 1.0000x reference)
//
#include <hip/hip_runtime.h>
#include <hip/hip_bf16.h>

// Problem constants (from reference): N=50000 nodes, R=16 relations,
// H=32 hidden, L=8 out, E=1600000 edges. ALL float tensors are f32.
#define Nn 50000
#define Rr 16
#define Hh 32
#define Ll 8
#define Ee 1600000
#define W2_STRIDE 260  // H*L = 256, +4 pad to break LDS bank alignment

// ---- counting: per-(rel,dst) counts for mean-norm, per-dst degree for CSR ----
__global__ __launch_bounds__(256) void count_kernel(
        const int* __restrict__ etype, const int* __restrict__ dst,
        int* __restrict__ cnt, int* __restrict__ deg) {
    int e = blockIdx.x * blockDim.x + threadIdx.x;
    if (e >= Ee) return;
    int d = dst[e], r = etype[e];
    atomicAdd(&cnt[r * Nn + d], 1);
    atomicAdd(&deg[d], 1);
}

// ---- 3-kernel exclusive prefix scan over deg[N] -> offs[N+1] ----
__global__ __launch_bounds__(256) void scan1_kernel(
        const int* __restrict__ deg, int* __restrict__ offs, int* __restrict__ bsum) {
    __shared__ int sm[256];
    int i = blockIdx.x * 256 + threadIdx.x;
    int v = (i < Nn) ? deg[i] : 0;
    sm[threadIdx.x] = v;
    __syncthreads();
    for (int off = 1; off < 256; off <<= 1) {
        int add = (threadIdx.x >= off) ? sm[threadIdx.x - off] : 0;
        __syncthreads();
        sm[threadIdx.x] += add;
        __syncthreads();
    }
    if (i < Nn) offs[i] = sm[threadIdx.x] - v;   // local exclusive
    if (threadIdx.x == 255) bsum[blockIdx.x] = sm[255];
}

__global__ __launch_bounds__(256) void scan2_kernel(
        const int* __restrict__ bsum, int* __restrict__ boff, int nblk) {
    __shared__ int sm[256];
    int v = (threadIdx.x < nblk) ? bsum[threadIdx.x] : 0;
    sm[threadIdx.x] = v;
    __syncthreads();
    for (int off = 1; off < 256; off <<= 1) {
        int add = (threadIdx.x >= off) ? sm[threadIdx.x - off] : 0;
        __syncthreads();
        sm[threadIdx.x] += add;
        __syncthreads();
    }
    if (threadIdx.x < nblk) boff[threadIdx.x] = sm[threadIdx.x] - v;  // exclusive
}

__global__ __launch_bounds__(256) void scan3_kernel(
        int* __restrict__ offs, const int* __restrict__ boff) {
    int i = blockIdx.x * 256 + threadIdx.x;
    if (i < Nn) offs[i] += boff[blockIdx.x];
    if (i == 0) offs[Nn] = Ee;
}

// ---- build CSR: csr[pos] = (rel<<16) | src  (src < 65536, rel < 16) ----
__global__ __launch_bounds__(256) void scatter_kernel(
        const int* __restrict__ src, const int* __restrict__ dst,
        const int* __restrict__ etype, const int* __restrict__ offs,
        int* __restrict__ cursor, int* __restrict__ csr) {
    int e = blockIdx.x * blockDim.x + threadIdx.x;
    if (e >= Ee) return;
    int d = dst[e];
    int pos = offs[d] + atomicAdd(&cursor[d], 1);
    csr[pos] = (etype[e] << 16) | src[e];
}

// ---- layer 1: h1[d] = relu(sum_e norm * W1[r, s, :] + root1[d] + b1) ----
// 8 threads per dst, each owning 4 of the 32 channels (one float4/lane;
// the 8 lanes of a dst-group fetch one contiguous 128B W1 row per edge).
__global__ __launch_bounds__(256) void layer1_kernel(
        const int* __restrict__ csr, const int* __restrict__ offs,
        const int* __restrict__ cnt,
        const float* __restrict__ W1,
        const float* __restrict__ root1,
        const float* __restrict__ b1,
        float* __restrict__ h1) {
    int t = blockIdx.x * blockDim.x + threadIdx.x;
    int d = t >> 3, c = t & 7;
    if (d >= Nn) return;
    int beg = offs[d], end = offs[d + 1];
    float4 acc = make_float4(0.f, 0.f, 0.f, 0.f);
    for (int e = beg; e < end; ++e) {
        int pk = csr[e];
        int s = pk & 0xffff, r = pk >> 16;
        float norm = 1.0f / (float)cnt[r * Nn + d];  // cnt>=1: this edge exists
        float4 w = *(const float4*)(W1 + (size_t)(r * Nn + s) * Hh + c * 4);
        acc.x += norm * w.x; acc.y += norm * w.y;
        acc.z += norm * w.z; acc.w += norm * w.w;
    }
    int hb = c * 4;
    const float4 rt = *(const float4*)(root1 + d * Hh + hb);
    const float4 bb = *(const float4*)(b1 + hb);
    float4 o;
    o.x = fmaxf(acc.x + rt.x + bb.x, 0.f);
    o.y = fmaxf(acc.y + rt.y + bb.y, 0.f);
    o.z = fmaxf(acc.z + rt.z + bb.z, 0.f);
    o.w = fmaxf(acc.w + rt.w + bb.w, 0.f);
    *(float4*)(h1 + d * Hh + hb) = o;
}

// ---- layer 2: out[d,l] = sigmoid( sum_e norm * (h1[s]·W2[r,:,l])
//                                   + h1[d]·root2[:,l] + b2[l] ) ----
// 8 threads per dst, one per output l. W2/root2/b2 staged in LDS.
__global__ __launch_bounds__(256) void layer2_kernel(
        const int* __restrict__ csr, const int* __restrict__ offs,
        const int* __restrict__ cnt, const float* __restrict__ h1,
        const float* __restrict__ W2,
        const float* __restrict__ root2,
        const float* __restrict__ b2,
        float* __restrict__ out) {
    __shared__ float W2s[Rr * W2_STRIDE];
    __shared__ float root2s[Hh * Ll];
    __shared__ float b2s[Ll];
    for (int idx = threadIdx.x; idx < Rr * Hh * Ll; idx += blockDim.x) {
        int r = idx >> 8, rem = idx & 255;
        W2s[r * W2_STRIDE + rem] = W2[idx];
    }
    for (int idx = threadIdx.x; idx < Hh * Ll; idx += blockDim.x)
        root2s[idx] = root2[idx];
    if (threadIdx.x < Ll) b2s[threadIdx.x] = b2[threadIdx.x];
    __syncthreads();

    int t = blockIdx.x * blockDim.x + threadIdx.x;
    int d = t >> 3, l = t & 7;
    if (d >= Nn) return;
    int beg = offs[d], end = offs[d + 1];
    float acc = 0.0f;
    for (int e = beg; e < end; ++e) {
        int pk = csr[e];
        int s = pk & 0xffff, r = pk >> 16;
        float norm = 1.0f / (float)cnt[r * Nn + d];
        const float4* hs = (const float4*)(h1 + s * Hh);
        const float* w = &W2s[r * W2_STRIDE + l];
        float dot = 0.0f;
#pragma unroll
        for (int q = 0; q < 8; ++q) {
            float4 hv = hs[q];
            dot += hv.x * w[(q * 4 + 0) * Ll] + hv.y * w[(q * 4 + 1) * Ll]
                 + hv.z * w[(q * 4 + 2) * Ll] + hv.w * w[(q * 4 + 3) * Ll];
        }
        acc += norm * dot;
    }
    const float* hd = h1 + d * Hh;
    float dot2 = 0.0f;
#pragma unroll
    for (int h = 0; h < Hh; ++h) dot2 += hd[h] * root2s[h * Ll + l];
    float o = acc + dot2 + b2s[l];
    out[d * Ll + l] = 1.0f / (1.0f + __expf(-o));
}

extern "C" void kernel_launch(void* const* d_in, const int* in_sizes, int n_in,
                              void* d_out, int out_size, void* d_ws, size_t ws_size,
                              hipStream_t stream) {
    const int* edge_index = (const int*)d_in[0];   // (2, E) int32
    const int* etype      = (const int*)d_in[1];   // (E,)  int32
    const float* W1    = (const float*)d_in[2];    // (R,N,H) f32
    const float* root1 = (const float*)d_in[3];    // (N,H)
    const float* b1    = (const float*)d_in[4];    // (H,)
    const float* W2    = (const float*)d_in[5];    // (R,H,L)
    const float* root2 = (const float*)d_in[6];    // (H,L)
    const float* b2    = (const float*)d_in[7];    // (L,)
    float* out = (float*)d_out;                    // (N, L) f32

    const int* src = edge_index;       // row 0
    const int* dst = edge_index + Ee;  // row 1

    // workspace layout (int32 units); total 4,160,000 ints = 16.64 MB
    int* ws     = (int*)d_ws;
    int* cnt    = ws;                  // [0,       800000)
    int* deg    = ws + 800000;         // [800000,  850000)
    int* offs   = ws + 850000;         // [850000,  900001)  N+1
    int* cursor = ws + 900016;         // [900016,  950016)
    int* bsum   = ws + 950016;         // 196
    int* boff   = ws + 950256;         // 196
    int* csr    = ws + 960000;         // [960000, 2560000)
    float* h1   = (float*)(ws + 2560000);  // N*H f32, ends at 4,160,000 ints

    if (ws_size < (size_t)4160000 * sizeof(int)) return;  // diagnostic guard

    // zero cnt/deg/cursor (ws is poisoned 0xAA before every call)
    hipMemsetAsync(d_ws, 0, (size_t)950016 * sizeof(int), stream);

    const int nblkE = (Ee + 255) / 256;
    const int nblkS = (Nn + 255) / 256;  // 196

    count_kernel<<<nblkE, 256, 0, stream>>>(etype, dst, cnt, deg);
    scan1_kernel<<<nblkS, 256, 0, stream>>>(deg, offs, bsum);
    scan2_kernel<<<1, 256, 0, stream>>>(bsum, boff, nblkS);
    scan3_kernel<<<nblkS, 256, 0, stream>>>(offs, boff);
    scatter_kernel<<<nblkE, 256, 0, stream>>>(src, dst, etype, offs, cursor, csr);
    layer1_kernel<<<(Nn * 8 + 255) / 256, 256, 0, stream>>>(csr, offs, cnt, W1, root1, b1, h1);
    layer2_kernel<<<(Nn * 8 + 255) / 256, 256, 0, stream>>>(csr, offs, cnt, h1, W2, root2, b2, out);
}

// Round 3
// 483.711 us; speedup vs baseline: 1.1092x; 1.1092x over previous
//
#include <hip/hip_runtime.h>
#include <hip/hip_bf16.h>

// RGCN: N=50000 nodes, R=16 relations, H=32 hidden, L=8 out, E=1600000 edges.
// All float tensors are f32 (verified round 2). Strategy: counting-sort edges
// by segment key seg = dst*16 + rel. Run boundaries in offs[] then give BOTH
// the per-dst CSR and the per-(rel,dst) mean-norm (1/runlen) -- no cnt reads,
// no rcp in the edge loops, and only 3.2M device-scope atomics total (was 4.8M).
#define Nn 50000
#define Rr 16
#define Hh 32
#define Ll 8
#define Ee 1600000
#define NSEG 800000            // N*R segments
#define W2_STRIDE 260          // H*L=256, +4 pad to break LDS bank alignment

// ---- count: one atomic per edge into cnt[dst*16+rel] ----
__global__ __launch_bounds__(256) void count_kernel(
        const int* __restrict__ etype, const int* __restrict__ dst,
        int* __restrict__ cnt) {
    int e = blockIdx.x * blockDim.x + threadIdx.x;
    if (e >= Ee) return;
    atomicAdd(&cnt[(dst[e] << 4) | etype[e]], 1);
}

// ---- exclusive scan over cnt[NSEG] -> offs[NSEG+1], 4 elems/thread ----
__global__ __launch_bounds__(256) void scan1_kernel(
        const int4* __restrict__ cnt4, int4* __restrict__ offs4,
        int* __restrict__ bsum) {
    __shared__ int sm[256];
    int i4 = blockIdx.x * 256 + threadIdx.x;           // int4 index
    int4 v = make_int4(0, 0, 0, 0);
    if (i4 < NSEG / 4) v = cnt4[i4];
    int s0 = v.x, s1 = s0 + v.y, s2 = s1 + v.z, s3 = s2 + v.w;
    sm[threadIdx.x] = s3;
    __syncthreads();
    for (int off = 1; off < 256; off <<= 1) {
        int add = (threadIdx.x >= off) ? sm[threadIdx.x - off] : 0;
        __syncthreads();
        sm[threadIdx.x] += add;
        __syncthreads();
    }
    int base = sm[threadIdx.x] - s3;                   // exclusive prefix of thread
    if (i4 < NSEG / 4)
        offs4[i4] = make_int4(base, base + s0, base + s1, base + s2);
    if (threadIdx.x == 255) bsum[blockIdx.x] = sm[255];
}

__global__ __launch_bounds__(1024) void scan2_kernel(
        const int* __restrict__ bsum, int* __restrict__ boff, int nblk) {
    __shared__ int sm[1024];
    int v = (threadIdx.x < nblk) ? bsum[threadIdx.x] : 0;
    sm[threadIdx.x] = v;
    __syncthreads();
    for (int off = 1; off < 1024; off <<= 1) {
        int add = (threadIdx.x >= off) ? sm[threadIdx.x - off] : 0;
        __syncthreads();
        sm[threadIdx.x] += add;
        __syncthreads();
    }
    if (threadIdx.x < nblk) boff[threadIdx.x] = sm[threadIdx.x] - v;  // exclusive
}

// add block offsets; also prefill cursor = final offs; set offs[NSEG]=Ee
__global__ __launch_bounds__(256) void scan3_kernel(
        int4* __restrict__ offs4, const int* __restrict__ boff,
        int4* __restrict__ cursor4, int* __restrict__ offs) {
    int i4 = blockIdx.x * 256 + threadIdx.x;
    if (i4 < NSEG / 4) {
        int b = boff[blockIdx.x];
        int4 v = offs4[i4];
        v.x += b; v.y += b; v.z += b; v.w += b;
        offs4[i4] = v;
        cursor4[i4] = v;
    }
    if (i4 == 0) offs[NSEG] = Ee;
}

// ---- scatter: csr[pos] = src (ushort), pos from per-segment cursor ----
__global__ __launch_bounds__(256) void scatter_kernel(
        const int* __restrict__ src, const int* __restrict__ dst,
        const int* __restrict__ etype, int* __restrict__ cursor,
        unsigned short* __restrict__ csr) {
    int e = blockIdx.x * blockDim.x + threadIdx.x;
    if (e >= Ee) return;
    int seg = (dst[e] << 4) | etype[e];
    int pos = atomicAdd(&cursor[seg], 1);
    csr[pos] = (unsigned short)src[e];
}

// ---- layer 1: h1[d] = relu(sum_runs norm_r * sum_e W1[r, s, :] + root1[d] + b1)
// 8 threads per dst, each owns 4 channels (one float4/lane; 8 lanes fetch one
// contiguous 128B W1 row per edge). Flat loop over the dst segment, tracking
// the current relation run from offs (norm = 1/runlen, updated at boundaries).
__global__ __launch_bounds__(256) void layer1_kernel(
        const unsigned short* __restrict__ csr, const int* __restrict__ offs,
        const float* __restrict__ W1, const float* __restrict__ root1,
        const float* __restrict__ b1, float* __restrict__ h1) {
    int t = blockIdx.x * blockDim.x + threadIdx.x;
    int d = t >> 3, c = t & 7;
    if (d >= Nn) return;
    int b16 = d << 4;
    int e = offs[b16];
    int eend = offs[b16 + 16];
    float4 acc = make_float4(0.f, 0.f, 0.f, 0.f);
    int r = -1;
    int rbeg = e, rend = e;            // forces run-advance on first edge
    float norm = 0.f;
    const float* Wr = W1;
    for (; e < eend; ++e) {
        if (e >= rend) {
            do { rbeg = rend; rend = offs[b16 + (++r) + 1]; } while (e >= rend);
            norm = 1.0f / (float)(rend - rbeg);
            Wr = W1 + (size_t)r * (Nn * Hh) + (c << 2);
        }
        int s = csr[e];
        float4 w = *(const float4*)(Wr + s * Hh);
        acc.x = fmaf(norm, w.x, acc.x);
        acc.y = fmaf(norm, w.y, acc.y);
        acc.z = fmaf(norm, w.z, acc.z);
        acc.w = fmaf(norm, w.w, acc.w);
    }
    int hb = c << 2;
    const float4 rt = *(const float4*)(root1 + d * Hh + hb);
    const float4 bb = *(const float4*)(b1 + hb);
    float4 o;
    o.x = fmaxf(acc.x + rt.x + bb.x, 0.f);
    o.y = fmaxf(acc.y + rt.y + bb.y, 0.f);
    o.z = fmaxf(acc.z + rt.z + bb.z, 0.f);
    o.w = fmaxf(acc.w + rt.w + bb.w, 0.f);
    *(float4*)(h1 + d * Hh + hb) = o;
}

// ---- layer 2: out[d,l] = sigmoid(sum_runs norm_r * sum_e (h1[s]·W2[r,:,l])
//                                  + h1[d]·root2[:,l] + b2[l])
// 8 threads per dst, one per output l; W2/root2/b2 staged in LDS.
__global__ __launch_bounds__(256) void layer2_kernel(
        const unsigned short* __restrict__ csr, const int* __restrict__ offs,
        const float* __restrict__ h1, const float* __restrict__ W2,
        const float* __restrict__ root2, const float* __restrict__ b2,
        float* __restrict__ out) {
    __shared__ float W2s[Rr * W2_STRIDE];
    __shared__ float root2s[Hh * Ll];
    __shared__ float b2s[Ll];
    for (int idx = threadIdx.x; idx < Rr * Hh * Ll; idx += blockDim.x) {
        int r = idx >> 8, rem = idx & 255;
        W2s[r * W2_STRIDE + rem] = W2[idx];
    }
    for (int idx = threadIdx.x; idx < Hh * Ll; idx += blockDim.x)
        root2s[idx] = root2[idx];
    if (threadIdx.x < Ll) b2s[threadIdx.x] = b2[threadIdx.x];
    __syncthreads();

    int t = blockIdx.x * blockDim.x + threadIdx.x;
    int d = t >> 3, l = t & 7;
    if (d >= Nn) return;
    int b16 = d << 4;
    int e = offs[b16];
    int eend = offs[b16 + 16];
    float acc = 0.0f;
    int r = -1;
    int rbeg = e, rend = e;
    float norm = 0.f;
    const float* w = W2s + l;
    for (; e < eend; ++e) {
        if (e >= rend) {
            do { rbeg = rend; rend = offs[b16 + (++r) + 1]; } while (e >= rend);
            norm = 1.0f / (float)(rend - rbeg);
            w = &W2s[r * W2_STRIDE + l];
        }
        int s = csr[e];
        const float4* hs = (const float4*)(h1 + s * Hh);
        float dot = 0.0f;
#pragma unroll
        for (int q = 0; q < 8; ++q) {
            float4 hv = hs[q];
            dot = fmaf(hv.x, w[(q * 4 + 0) * Ll], dot);
            dot = fmaf(hv.y, w[(q * 4 + 1) * Ll], dot);
            dot = fmaf(hv.z, w[(q * 4 + 2) * Ll], dot);
            dot = fmaf(hv.w, w[(q * 4 + 3) * Ll], dot);
        }
        acc = fmaf(norm, dot, acc);
    }
    const float* hd = h1 + d * Hh;
    float dot2 = 0.0f;
#pragma unroll
    for (int h = 0; h < Hh; ++h) dot2 = fmaf(hd[h], root2s[h * Ll + l], dot2);
    float o = acc + dot2 + b2s[l];
    out[d * Ll + l] = 1.0f / (1.0f + __expf(-o));
}

extern "C" void kernel_launch(void* const* d_in, const int* in_sizes, int n_in,
                              void* d_out, int out_size, void* d_ws, size_t ws_size,
                              hipStream_t stream) {
    const int* edge_index = (const int*)d_in[0];   // (2, E) int32
    const int* etype      = (const int*)d_in[1];   // (E,)  int32
    const float* W1    = (const float*)d_in[2];    // (R,N,H) f32
    const float* root1 = (const float*)d_in[3];    // (N,H)
    const float* b1    = (const float*)d_in[4];    // (H,)
    const float* W2    = (const float*)d_in[5];    // (R,H,L)
    const float* root2 = (const float*)d_in[6];    // (H,L)
    const float* b2    = (const float*)d_in[7];    // (L,)
    float* out = (float*)d_out;                    // (N, L) f32

    const int* src = edge_index;       // row 0
    const int* dst = edge_index + Ee;  // row 1

    // workspace layout (int32 units), overlays exploit liveness:
    //   offs   [0,       800016)   NSEG+1 (+pad)            persistent
    //   csr    [800016,  1600016)  1.6M ushort = 800000 int  written in scatter
    //   cnt    [1600016, 2400016)  live count..scan1 only
    //   cursor [1600016, 2400016)  SAME region; scan3 rewrites it fully
    //   h1     [2400016, 4000016)  N*H f32, written in layer1
    //   bsum   [4000016, 4000800)  782+pad
    //   boff   [4000800, 4001600)
    // total 4,001,600 ints = 16.01 MB (round-2 verified ws >= 16.64 MB)
    int* ws = (int*)d_ws;
    int* offs            = ws;
    unsigned short* csr  = (unsigned short*)(ws + 800016);
    int* cnt             = ws + 1600016;
    int* cursor          = ws + 1600016;
    float* h1            = (float*)(ws + 2400016);
    int* bsum            = ws + 4000016;
    int* boff            = ws + 4000800;

    if (ws_size < (size_t)4001600 * sizeof(int)) return;  // diagnostic guard

    // zero only cnt (ws is poisoned 0xAA before every call)
    hipMemsetAsync(cnt, 0, (size_t)NSEG * sizeof(int), stream);

    const int nblkE = (Ee + 255) / 256;           // 6250
    const int nblkS = (NSEG / 4 + 255) / 256;     // 782 (200000 int4s)

    count_kernel<<<nblkE, 256, 0, stream>>>(etype, dst, cnt);
    scan1_kernel<<<nblkS, 256, 0, stream>>>((const int4*)cnt, (int4*)offs, bsum);
    scan2_kernel<<<1, 1024, 0, stream>>>(bsum, boff, nblkS);
    scan3_kernel<<<nblkS, 256, 0, stream>>>((int4*)offs, boff, (int4*)cursor, offs);
    scatter_kernel<<<nblkE, 256, 0, stream>>>(src, dst, etype, cursor, csr);
    layer1_kernel<<<(Nn * 8 + 255) / 256, 256, 0, stream>>>(csr, offs, W1, root1, b1, h1);
    layer2_kernel<<<(Nn * 8 + 255) / 256, 256, 0, stream>>>(csr, offs, h1, W2, root2, b2, out);
}

// Round 4
// 406.480 us; speedup vs baseline: 1.3200x; 1.1900x over previous
//
#include <hip/hip_runtime.h>
#include <hip/hip_bf16.h>

// RGCN: N=50000, R=16, H=32, L=8, E=1600000. All float tensors f32.
// Build: single-atomic-pass counting sort by seg = dst*16 + rel.
//   rank_kernel:  rank = atomicAdd(cnt[seg],1), pack[e] = (seg<<8)|rank
//   scan:         combo[seg] = (offs<<8) | cnt   (offs<2^21, cnt<2^8)
//   place_kernel: csr32[offs+rank] = (rel<<24)|(cnt<<16)|src   (atomic-free)
// Layers: flat branchless loops; per edge ONE broadcast csr32 load carries
// src+rel+segcount; norm via exact 256-entry LDS reciprocal table.
#define Nn 50000
#define Rr 16
#define Hh 32
#define Ll 8
#define Ee 1600000
#define NSEG 800000
#define W2_STRIDE 260  // H*L=256, +4 pad to break LDS bank alignment

// ---- pass 1: count + rank in one atomic ----
__global__ __launch_bounds__(256) void rank_kernel(
        const int* __restrict__ etype, const int* __restrict__ dst,
        int* __restrict__ cnt, unsigned* __restrict__ pack) {
    int e = blockIdx.x * blockDim.x + threadIdx.x;
    if (e >= Ee) return;
    unsigned seg = (unsigned)((dst[e] << 4) | etype[e]);
    unsigned rank = (unsigned)atomicAdd(&cnt[seg], 1);
    pack[e] = (seg << 8) | rank;
}

// ---- exclusive scan over cnt[NSEG], 4 elems/thread ----
__global__ __launch_bounds__(256) void scan1_kernel(
        const int4* __restrict__ cnt4, int4* __restrict__ offs4,
        int* __restrict__ bsum) {
    __shared__ int sm[256];
    int i4 = blockIdx.x * 256 + threadIdx.x;
    int4 v = make_int4(0, 0, 0, 0);
    if (i4 < NSEG / 4) v = cnt4[i4];
    int s0 = v.x, s1 = s0 + v.y, s2 = s1 + v.z, s3 = s2 + v.w;
    sm[threadIdx.x] = s3;
    __syncthreads();
    for (int off = 1; off < 256; off <<= 1) {
        int add = (threadIdx.x >= off) ? sm[threadIdx.x - off] : 0;
        __syncthreads();
        sm[threadIdx.x] += add;
        __syncthreads();
    }
    int base = sm[threadIdx.x] - s3;
    if (i4 < NSEG / 4)
        offs4[i4] = make_int4(base, base + s0, base + s1, base + s2);
    if (threadIdx.x == 255) bsum[blockIdx.x] = sm[255];
}

__global__ __launch_bounds__(1024) void scan2_kernel(
        const int* __restrict__ bsum, int* __restrict__ boff, int nblk) {
    __shared__ int sm[1024];
    int v = (threadIdx.x < nblk) ? bsum[threadIdx.x] : 0;
    sm[threadIdx.x] = v;
    __syncthreads();
    for (int off = 1; off < 1024; off <<= 1) {
        int add = (threadIdx.x >= off) ? sm[threadIdx.x - off] : 0;
        __syncthreads();
        sm[threadIdx.x] += add;
        __syncthreads();
    }
    if (threadIdx.x < nblk) boff[threadIdx.x] = sm[threadIdx.x] - v;
}

// finalize: combo[seg] = ((offs+boff)<<8) | cnt ; combo[NSEG] = Ee<<8
__global__ __launch_bounds__(256) void scan3_kernel(
        int4* __restrict__ offs4, const int* __restrict__ boff,
        const int4* __restrict__ cnt4, int* __restrict__ combo) {
    int i4 = blockIdx.x * 256 + threadIdx.x;
    if (i4 < NSEG / 4) {
        int b = boff[blockIdx.x];
        int4 v = offs4[i4];
        int4 c = cnt4[i4];
        int4 o;
        o.x = ((v.x + b) << 8) | c.x;
        o.y = ((v.y + b) << 8) | c.y;
        o.z = ((v.z + b) << 8) | c.z;
        o.w = ((v.w + b) << 8) | c.w;
        offs4[i4] = o;   // combo, in place
    }
    if (i4 == 0) combo[NSEG] = (Ee << 8);
}

// ---- pass 2: atomic-free placement ----
__global__ __launch_bounds__(256) void place_kernel(
        const int* __restrict__ src, const unsigned* __restrict__ pack,
        const unsigned* __restrict__ combo, unsigned* __restrict__ csr32) {
    int e = blockIdx.x * blockDim.x + threadIdx.x;
    if (e >= Ee) return;
    unsigned p = pack[e];
    unsigned seg = p >> 8, rank = p & 255u;
    unsigned c = combo[seg];
    unsigned pos = (c >> 8) + rank;
    unsigned k = c & 255u;           // segment count
    unsigned r = seg & 15u;          // relation
    csr32[pos] = (r << 24) | (k << 16) | (unsigned)src[e];
}

// ---- layer 1: h1[d] = relu(sum_e (1/k_e) * W1[r_e, s_e, :] + root1[d] + b1)
// 8 threads per dst, each owns 4 channels; flat branchless edge loop.
__global__ __launch_bounds__(256) void layer1_kernel(
        const unsigned* __restrict__ csr32, const unsigned* __restrict__ combo,
        const float* __restrict__ W1, const float* __restrict__ root1,
        const float* __restrict__ b1, float* __restrict__ h1) {
    __shared__ float rcp_tab[256];
    rcp_tab[threadIdx.x] = 1.0f / (float)(threadIdx.x ? threadIdx.x : 1);
    __syncthreads();
    int t = blockIdx.x * blockDim.x + threadIdx.x;
    int d = t >> 3, c = t & 7;
    if (d >= Nn) return;
    int e    = (int)(combo[d << 4] >> 8);
    int eend = (int)(combo[(d + 1) << 4] >> 8);
    float4 acc = make_float4(0.f, 0.f, 0.f, 0.f);
    const float* Wc = W1 + (c << 2);
    for (; e < eend; ++e) {
        unsigned v = csr32[e];
        int s = v & 0xffffu;
        float norm = rcp_tab[(v >> 16) & 255u];
        int r = v >> 24;
        float4 w = *(const float4*)(Wc + ((size_t)r * Nn + s) * Hh);
        acc.x = fmaf(norm, w.x, acc.x);
        acc.y = fmaf(norm, w.y, acc.y);
        acc.z = fmaf(norm, w.z, acc.z);
        acc.w = fmaf(norm, w.w, acc.w);
    }
    int hb = c << 2;
    const float4 rt = *(const float4*)(root1 + d * Hh + hb);
    const float4 bb = *(const float4*)(b1 + hb);
    float4 o;
    o.x = fmaxf(acc.x + rt.x + bb.x, 0.f);
    o.y = fmaxf(acc.y + rt.y + bb.y, 0.f);
    o.z = fmaxf(acc.z + rt.z + bb.z, 0.f);
    o.w = fmaxf(acc.w + rt.w + bb.w, 0.f);
    *(float4*)(h1 + d * Hh + hb) = o;
}

// ---- layer 2: out[d,l] = sigmoid(sum_e (1/k_e)*(h1[s_e]·W2[r_e,:,l])
//                                  + h1[d]·root2[:,l] + b2[l])
// 8 threads per dst, one per output l; flat branchless edge loop.
__global__ __launch_bounds__(256) void layer2_kernel(
        const unsigned* __restrict__ csr32, const unsigned* __restrict__ combo,
        const float* __restrict__ h1, const float* __restrict__ W2,
        const float* __restrict__ root2, const float* __restrict__ b2,
        float* __restrict__ out) {
    __shared__ float W2s[Rr * W2_STRIDE];
    __shared__ float root2s[Hh * Ll];
    __shared__ float b2s[Ll];
    __shared__ float rcp_tab[256];
    rcp_tab[threadIdx.x] = 1.0f / (float)(threadIdx.x ? threadIdx.x : 1);
    for (int idx = threadIdx.x; idx < Rr * Hh * Ll; idx += blockDim.x) {
        int r = idx >> 8, rem = idx & 255;
        W2s[r * W2_STRIDE + rem] = W2[idx];
    }
    for (int idx = threadIdx.x; idx < Hh * Ll; idx += blockDim.x)
        root2s[idx] = root2[idx];
    if (threadIdx.x < Ll) b2s[threadIdx.x] = b2[threadIdx.x];
    __syncthreads();

    int t = blockIdx.x * blockDim.x + threadIdx.x;
    int d = t >> 3, l = t & 7;
    if (d >= Nn) return;
    int e    = (int)(combo[d << 4] >> 8);
    int eend = (int)(combo[(d + 1) << 4] >> 8);
    float acc = 0.0f;
    for (; e < eend; ++e) {
        unsigned v = csr32[e];
        int s = v & 0xffffu;
        float norm = rcp_tab[(v >> 16) & 255u];
        int r = v >> 24;
        const float4* hs = (const float4*)(h1 + s * Hh);
        const float* w = &W2s[r * W2_STRIDE + l];
        float dot = 0.0f;
#pragma unroll
        for (int q = 0; q < 8; ++q) {
            float4 hv = hs[q];
            dot = fmaf(hv.x, w[(q * 4 + 0) * Ll], dot);
            dot = fmaf(hv.y, w[(q * 4 + 1) * Ll], dot);
            dot = fmaf(hv.z, w[(q * 4 + 2) * Ll], dot);
            dot = fmaf(hv.w, w[(q * 4 + 3) * Ll], dot);
        }
        acc = fmaf(norm, dot, acc);
    }
    const float* hd = h1 + d * Hh;
    float dot2 = 0.0f;
#pragma unroll
    for (int h = 0; h < Hh; ++h) dot2 = fmaf(hd[h], root2s[h * Ll + l], dot2);
    float o = acc + dot2 + b2s[l];
    out[d * Ll + l] = 1.0f / (1.0f + __expf(-o));
}

extern "C" void kernel_launch(void* const* d_in, const int* in_sizes, int n_in,
                              void* d_out, int out_size, void* d_ws, size_t ws_size,
                              hipStream_t stream) {
    const int* edge_index = (const int*)d_in[0];   // (2, E) int32
    const int* etype      = (const int*)d_in[1];   // (E,)  int32
    const float* W1    = (const float*)d_in[2];    // (R,N,H) f32
    const float* root1 = (const float*)d_in[3];    // (N,H)
    const float* b1    = (const float*)d_in[4];    // (H,)
    const float* W2    = (const float*)d_in[5];    // (R,H,L)
    const float* root2 = (const float*)d_in[6];    // (H,L)
    const float* b2    = (const float*)d_in[7];    // (L,)
    float* out = (float*)d_out;                    // (N, L) f32

    const int* src = edge_index;       // row 0
    const int* dst = edge_index + Ee;  // row 1

    // workspace (int32 units), overlays by liveness:
    //   combo  [0,       800016)   scan1 partial offs -> scan3 combo; ->layers
    //   csr32  [800016,  2400016)  written in place (after scan3)
    //   cnt    [800016,  1600016)  SAME region as csr32 lo; dead after scan3
    //   pack   [2400016, 4000016)  rank_kernel -> place_kernel
    //   h1     [2400016, 4000016)  SAME region; written in layer1 (pack dead)
    //   bsum   [4000016, 4000800), boff [4000800, 4001616)
    // total 4,001,616 ints = 16.01 MB (<= 16.64 MB proven available)
    int* ws = (int*)d_ws;
    int* combo          = ws;
    int* cnt            = ws + 800016;
    unsigned* csr32     = (unsigned*)(ws + 800016);
    unsigned* pack      = (unsigned*)(ws + 2400016);
    float* h1           = (float*)(ws + 2400016);
    int* bsum           = ws + 4000016;
    int* boff           = ws + 4000800;

    if (ws_size < (size_t)4001616 * sizeof(int)) return;  // diagnostic guard

    hipMemsetAsync(cnt, 0, (size_t)NSEG * sizeof(int), stream);

    const int nblkE = (Ee + 255) / 256;           // 6250
    const int nblkS = (NSEG / 4 + 255) / 256;     // 782

    rank_kernel<<<nblkE, 256, 0, stream>>>(etype, dst, cnt, pack);
    scan1_kernel<<<nblkS, 256, 0, stream>>>((const int4*)cnt, (int4*)combo, bsum);
    scan2_kernel<<<1, 1024, 0, stream>>>(bsum, boff, nblkS);
    scan3_kernel<<<nblkS, 256, 0, stream>>>((int4*)combo, boff, (const int4*)cnt, combo);
    place_kernel<<<nblkE, 256, 0, stream>>>(src, pack, (const unsigned*)combo, csr32);
    layer1_kernel<<<(Nn * 8 + 255) / 256, 256, 0, stream>>>(csr32, (const unsigned*)combo, W1, root1, b1, h1);
    layer2_kernel<<<(Nn * 8 + 255) / 256, 256, 0, stream>>>(csr32, (const unsigned*)combo, h1, W2, root2, b2, out);
}